// Round 3
// baseline (6826.267 us; speedup 1.0000x reference)
//
#include <hip/hip_runtime.h>

// ---------------------------------------------------------------------------
// GCNConvNet: 2x GIN conv (shared aggregation) + dense head.
// Round 3: I/O dtypes corrected to fp32 (reference dtype; harness converts
// only int64->int32). bf16 is used INTERNALLY for MFMA; harness grants bf16
// tolerance (2% threshold). Round-2 NaN attributed to reading fp32 as bf16.
//   - agg via f32 atomics, h0 = bf16(x+agg) once (shared by both branches)
//   - weights transpose+downcast fp32[K,N] -> bf16[N,K]
//   - m97-style GEMM: 128x128 tile, BK=32, global_load_lds(16B), 16x16x32 bf16
//   - final layer stores fp32 to d_out
// ---------------------------------------------------------------------------

#define NN 60000
#define NE 960000
#define C_IN 128
#define HID 512
#define DCAT 1024
#define DFC 2048
#define DL1 4096
#define OUTC 64

typedef __bf16 bf16x8 __attribute__((ext_vector_type(8)));
typedef float floatx4 __attribute__((ext_vector_type(4)));

__device__ __forceinline__ unsigned short f2b(float f) {
  unsigned int u = __float_as_uint(f);
  unsigned int r = (u + 0x7fffu + ((u >> 16) & 1u)) >> 16;  // RNE, finite inputs
  return (unsigned short)r;
}

// async global->LDS, 16B per lane; LDS dest = wave-uniform base + lane*16
#define GLOAD_LDS16(g, l)                                                     \
  __builtin_amdgcn_global_load_lds(                                           \
      (__attribute__((address_space(1))) void*)(g),                           \
      (__attribute__((address_space(3))) void*)(l), 16, 0, 0)

// ---------------------------------------------------------------------------
// BN param fold: scale = gamma*rsqrt(var+eps); shift = (b1-mean)*scale + beta
__global__ void k_bnparams(const float* __restrict__ g,
                           const float* __restrict__ be,
                           const float* __restrict__ mn,
                           const float* __restrict__ vr,
                           const float* __restrict__ b1,
                           float* __restrict__ scale, float* __restrict__ shift) {
  int i = blockIdx.x * 256 + threadIdx.x;
  if (i < HID) {
    float s = g[i] * rsqrtf(vr[i] + 1e-5f);
    scale[i] = s;
    shift[i] = (b1[i] - mn[i]) * s + be[i];
  }
}

// fp32 [K,N] -> bf16 [N,K] transpose+downcast, 32x32 tiles
__global__ void k_transpose(const float* __restrict__ in,
                            unsigned short* __restrict__ out, int K, int N) {
  __shared__ float t[32][33];
  int n0 = blockIdx.x * 32, k0 = blockIdx.y * 32;
  int tx = threadIdx.x & 31, ty = threadIdx.x >> 5;  // 32 x 8
#pragma unroll
  for (int i = 0; i < 32; i += 8)
    t[ty + i][tx] = in[(size_t)(k0 + ty + i) * N + n0 + tx];
  __syncthreads();
#pragma unroll
  for (int i = 0; i < 32; i += 8)
    out[(size_t)(n0 + ty + i) * K + k0 + tx] = f2b(t[tx][ty + i]);
}

// edge scatter: agg[dst] += x[src]  (f32 atomics, 2 channels/lane)
__global__ void k_scatter(const float2* __restrict__ x2,
                          const int* __restrict__ src,
                          const int* __restrict__ dst,
                          float* __restrict__ agg) {
  int e = blockIdx.x * 4 + (threadIdx.x >> 6);
  int lane = threadIdx.x & 63;
  int s = src[e], d = dst[e];
  float2 u = x2[(size_t)s * 64 + lane];
  atomicAdd(&agg[(size_t)d * 128 + lane * 2], u.x);
  atomicAdd(&agg[(size_t)d * 128 + lane * 2 + 1], u.y);
}

// h0 = bf16(x + agg), 4 elems/thread
__global__ void k_cast_h0(const float4* __restrict__ x4,
                          const float4* __restrict__ agg4,
                          uint2* __restrict__ h04, int n4) {
  int i = blockIdx.x * blockDim.x + threadIdx.x;
  if (i >= n4) return;
  float4 xu = x4[i];
  float4 a = agg4[i];
  float r0 = a.x + xu.x, r1 = a.y + xu.y, r2 = a.z + xu.z, r3 = a.w + xu.w;
  uint2 o;
  o.x = (unsigned)f2b(r0) | ((unsigned)f2b(r1) << 16);
  o.y = (unsigned)f2b(r2) | ((unsigned)f2b(r3) << 16);
  h04[i] = o;
}

// ---------------------------------------------------------------------------
// GEMM: C[M,N] = A[M,K] @ Bt[N,K]^T, bf16 in, f32 accum, bf16 out (fp32 for
// EPI==4, the network output). 128x128 tile, BK=32, 4 waves (2x2), each wave
// 64x64 via 4x4 MFMA 16x16x32_bf16. LDS layout [oct=k/8][row][8 shorts]:
// global_load_lds contiguity (lane i -> base+16i), frag reads 2-way aliased
// (free per m136).
// EPI: 0=bias, 1=bias+relu, 2=bn(scale,shift)+relu, 3=bias+leaky, 4=bias+sigmoid->fp32
template <int EPI>
__global__ __launch_bounds__(256) void k_gemm(
    const unsigned short* __restrict__ A, const unsigned short* __restrict__ Bt,
    unsigned short* __restrict__ C, const float* __restrict__ bias,
    const float* __restrict__ scale, const float* __restrict__ shift,
    int M, int N, int K, int ldc) {
  __shared__ __align__(16) unsigned short lsA[4][128][8];
  __shared__ __align__(16) unsigned short lsB[4][128][8];

  const int tid = threadIdx.x;
  const int w = tid >> 6;
  const int lane = tid & 63;
  const int quad = lane >> 4;
  const int r16 = lane & 15;
  const int wm = w >> 1, wn = w & 1;
  const int m0 = blockIdx.x * 128;
  const int n0 = blockIdx.y * 128;

  // staging rows (clamped for edge tiles; stores are masked below)
  const int ra0 = min(m0 + lane, M - 1);
  const int ra1 = min(m0 + 64 + lane, M - 1);
  const int rb0 = min(n0 + lane, N - 1);
  const int rb1 = min(n0 + 64 + lane, N - 1);
  const unsigned short* pA0 = A + (size_t)ra0 * K + w * 8;
  const unsigned short* pA1 = A + (size_t)ra1 * K + w * 8;
  const unsigned short* pB0 = Bt + (size_t)rb0 * K + w * 8;
  const unsigned short* pB1 = Bt + (size_t)rb1 * K + w * 8;

  floatx4 acc[4][4];
#pragma unroll
  for (int i = 0; i < 4; i++)
#pragma unroll
    for (int j = 0; j < 4; j++) acc[i][j] = (floatx4){0.f, 0.f, 0.f, 0.f};

  for (int k0 = 0; k0 < K; k0 += 32) {
    GLOAD_LDS16(pA0, &lsA[w][0][0]);
    GLOAD_LDS16(pA1, &lsA[w][64][0]);
    GLOAD_LDS16(pB0, &lsB[w][0][0]);
    GLOAD_LDS16(pB1, &lsB[w][64][0]);
    pA0 += 32; pA1 += 32; pB0 += 32; pB1 += 32;
    __syncthreads();  // compiler drains vmcnt before s_barrier (m97 pattern)

    bf16x8 af[4], bfr[4];
#pragma unroll
    for (int i = 0; i < 4; i++)
      af[i] = *(const bf16x8*)&lsA[quad][wm * 64 + i * 16 + r16][0];
#pragma unroll
    for (int j = 0; j < 4; j++)
      bfr[j] = *(const bf16x8*)&lsB[quad][wn * 64 + j * 16 + r16][0];
#pragma unroll
    for (int i = 0; i < 4; i++)
#pragma unroll
      for (int j = 0; j < 4; j++)
        acc[i][j] = __builtin_amdgcn_mfma_f32_16x16x32_bf16(af[i], bfr[j],
                                                            acc[i][j], 0, 0, 0);
    __syncthreads();
  }

  // epilogue: C/D layout col=lane&15, row=quad*4+reg  [m89-verified]
#pragma unroll
  for (int j = 0; j < 4; j++) {
    int gn = n0 + wn * 64 + j * 16 + r16;
    int cn = gn < N ? gn : 0;
    float p0, p1 = 0.f;
    if constexpr (EPI == 2) {
      p0 = scale[cn];
      p1 = shift[cn];
    } else {
      p0 = bias[cn];
    }
#pragma unroll
    for (int i = 0; i < 4; i++) {
#pragma unroll
      for (int t = 0; t < 4; t++) {
        int gm = m0 + wm * 64 + i * 16 + quad * 4 + t;
        if (gm < M && gn < N) {
          float v = acc[i][j][t];
          if constexpr (EPI == 0) {
            v += p0;
            C[(size_t)gm * ldc + gn] = f2b(v);
          } else if constexpr (EPI == 1) {
            v += p0; v = v > 0.f ? v : 0.f;
            C[(size_t)gm * ldc + gn] = f2b(v);
          } else if constexpr (EPI == 2) {
            v = v * p0 + p1; v = v > 0.f ? v : 0.f;
            C[(size_t)gm * ldc + gn] = f2b(v);
          } else if constexpr (EPI == 3) {
            v += p0; v = v > 0.f ? v : 0.01f * v;
            C[(size_t)gm * ldc + gn] = f2b(v);
          } else {  // sigmoid -> fp32 network output
            v += p0;
            v = 1.f / (1.f + __expf(-v));
            ((float*)C)[(size_t)gm * ldc + gn] = v;
          }
        }
      }
    }
  }
}

// ---------------------------------------------------------------------------
extern "C" void kernel_launch(void* const* d_in, const int* in_sizes, int n_in,
                              void* d_out, int out_size, void* d_ws,
                              size_t ws_size, hipStream_t stream) {
  typedef const float* cf;
  cf x = (cf)d_in[0];
  const int* ei = (const int*)d_in[1];
  const int* srcI = ei;
  const int* dstI = ei + NE;
  cf w1a = (cf)d_in[2],  b1a = (cf)d_in[3];
  cf ga = (cf)d_in[4],   bea = (cf)d_in[5];
  cf mna = (cf)d_in[6],  vra = (cf)d_in[7];
  cf w2a = (cf)d_in[8],  b2a = (cf)d_in[9];
  cf w1b = (cf)d_in[10], b1b = (cf)d_in[11];
  cf gb = (cf)d_in[12],  beb = (cf)d_in[13];
  cf mnb = (cf)d_in[14], vrb = (cf)d_in[15];
  cf w2b = (cf)d_in[16], b2b = (cf)d_in[17];
  cf fc_w = (cf)d_in[18], fc_b = (cf)d_in[19];
  cf l1_w = (cf)d_in[20], l1_b = (cf)d_in[21];
  cf l2_w = (cf)d_in[22], l2_b = (cf)d_in[23];
  cf ow = (cf)d_in[24],   ob = (cf)d_in[25];
  unsigned short* out = (unsigned short*)d_out;  // actually fp32; cast in EPI4

  // ---- workspace carve-up, bounded by ws_size --------------------------------
  char* ws = (char*)d_ws;
  size_t off = 0;
  auto carve = [&](size_t bytes) {
    void* p = ws + off;
    off += (bytes + 255) & ~(size_t)255;
    return p;
  };
  // fixed footprint (~86 MB)
  unsigned short* wt1a = (unsigned short*)carve((size_t)HID * C_IN * 2);
  unsigned short* wt2a = (unsigned short*)carve((size_t)HID * HID * 2);
  unsigned short* wt1b = (unsigned short*)carve((size_t)HID * C_IN * 2);
  unsigned short* wt2b = (unsigned short*)carve((size_t)HID * HID * 2);
  unsigned short* wtfc = (unsigned short*)carve((size_t)DFC * DCAT * 2);
  unsigned short* wtl1 = (unsigned short*)carve((size_t)DL1 * DFC * 2);
  unsigned short* wtl2 = (unsigned short*)carve((size_t)DFC * DL1 * 2);
  unsigned short* wtout = (unsigned short*)carve((size_t)OUTC * DFC * 2);
  float* scale_a = (float*)carve(HID * 4);
  float* shift_a = (float*)carve(HID * 4);
  float* scale_b = (float*)carve(HID * 4);
  float* shift_b = (float*)carve(HID * 4);
  float* agg = (float*)carve((size_t)NN * C_IN * 4);
  unsigned short* h0 = (unsigned short*)carve((size_t)NN * C_IN * 2);

  // dynamic footprint: bufA = mchunk x 2048, bufB = mchunk x 4096 (bf16)
  size_t rem = (ws_size > off + 4096) ? (ws_size - off - 4096) : 0;
  int mchunk = (int)(rem / 12288u);
  if (mchunk > 15000) mchunk = 15000;
  mchunk &= ~127;
  if (mchunk < 128) mchunk = 128;
  unsigned short* bufA = (unsigned short*)carve((size_t)mchunk * DFC * 2);
  unsigned short* bufB = (unsigned short*)carve((size_t)mchunk * DL1 * 2);
  (void)in_sizes; (void)n_in; (void)out_size;

  // ---- 1. params + weight transposes + aggregation ---------------------------
  hipMemsetAsync(agg, 0, (size_t)NN * C_IN * 4, stream);
  k_bnparams<<<2, 256, 0, stream>>>(ga, bea, mna, vra, b1a, scale_a, shift_a);
  k_bnparams<<<2, 256, 0, stream>>>(gb, beb, mnb, vrb, b1b, scale_b, shift_b);

  k_transpose<<<dim3(HID / 32, C_IN / 32), 256, 0, stream>>>(w1a, wt1a, C_IN, HID);
  k_transpose<<<dim3(HID / 32, HID / 32), 256, 0, stream>>>(w2a, wt2a, HID, HID);
  k_transpose<<<dim3(HID / 32, C_IN / 32), 256, 0, stream>>>(w1b, wt1b, C_IN, HID);
  k_transpose<<<dim3(HID / 32, HID / 32), 256, 0, stream>>>(w2b, wt2b, HID, HID);
  k_transpose<<<dim3(DFC / 32, DCAT / 32), 256, 0, stream>>>(fc_w, wtfc, DCAT, DFC);
  k_transpose<<<dim3(DL1 / 32, DFC / 32), 256, 0, stream>>>(l1_w, wtl1, DFC, DL1);
  k_transpose<<<dim3(DFC / 32, DL1 / 32), 256, 0, stream>>>(l2_w, wtl2, DL1, DFC);
  k_transpose<<<dim3(OUTC / 32, DFC / 32), 256, 0, stream>>>(ow, wtout, DFC, OUTC);

  k_scatter<<<NE / 4, 256, 0, stream>>>((const float2*)x, srcI, dstI, agg);
  k_cast_h0<<<(NN * C_IN / 4 + 255) / 256, 256, 0, stream>>>(
      (const float4*)x, (const float4*)agg, (uint2*)h0, NN * C_IN / 4);

  // ---- 2. GEMM chain, M in adaptive chunks -----------------------------------
  auto gemm = [&](int epi, const unsigned short* A, const unsigned short* Bt,
                  unsigned short* Cp, cf bias, const float* sc, const float* sh,
                  int M, int N, int K, int ldc) {
    dim3 g((M + 127) / 128, (N + 127) / 128);
    switch (epi) {
      case 0: k_gemm<0><<<g, 256, 0, stream>>>(A, Bt, Cp, bias, sc, sh, M, N, K, ldc); break;
      case 1: k_gemm<1><<<g, 256, 0, stream>>>(A, Bt, Cp, bias, sc, sh, M, N, K, ldc); break;
      case 2: k_gemm<2><<<g, 256, 0, stream>>>(A, Bt, Cp, bias, sc, sh, M, N, K, ldc); break;
      case 3: k_gemm<3><<<g, 256, 0, stream>>>(A, Bt, Cp, bias, sc, sh, M, N, K, ldc); break;
      default: k_gemm<4><<<g, 256, 0, stream>>>(A, Bt, Cp, bias, sc, sh, M, N, K, ldc); break;
    }
  };

  for (int m0 = 0; m0 < NN; m0 += mchunk) {
    const int M = (NN - m0 < mchunk) ? (NN - m0) : mchunk;
    const unsigned short* h0c = h0 + (size_t)m0 * C_IN;
    unsigned short* outc = out + (size_t)m0 * OUTC * 2;  // fp32 rows (2 shorts/elem)
    // branch A: Linear+BN+ReLU -> bufA ; Linear+ReLU -> bufB[:, :512]
    gemm(2, h0c, wt1a, bufA, nullptr, scale_a, shift_a, M, HID, C_IN, HID);
    gemm(1, bufA, wt2a, bufB, b2a, nullptr, nullptr, M, HID, HID, DCAT);
    // branch B -> bufB[:, 512:]
    gemm(2, h0c, wt1b, bufA, nullptr, scale_b, shift_b, M, HID, C_IN, HID);
    gemm(1, bufA, wt2b, bufB + HID, b2b, nullptr, nullptr, M, HID, HID, DCAT);
    // head: xcat(bufB,1024) -> hfc(bufA,2048) -> hl1(bufB,4096) -> hl2(bufA,2048) -> out(fp32)
    gemm(3, bufB, wtfc, bufA, fc_b, nullptr, nullptr, M, DFC, DCAT, DFC);
    gemm(0, bufA, wtl1, bufB, l1_b, nullptr, nullptr, M, DL1, DFC, DL1);
    gemm(0, bufB, wtl2, bufA, l2_b, nullptr, nullptr, M, DFC, DL1, DFC);
    gemm(4, bufA, wtout, outc, ob, nullptr, nullptr, M, OUTC, DFC, OUTC);
  }
}

// Round 4
// 5946.001 us; speedup vs baseline: 1.1480x; 1.1480x over previous
//
#include <hip/hip_runtime.h>

// ---------------------------------------------------------------------------
// GCNConvNet: 2x GIN conv (shared aggregation) + dense head. fp32 I/O,
// bf16 MFMA internally (harness grants bf16 tolerance).
// Round 4: (a) atomic scatter -> CSR build + wave-per-node gather (removes
// 786us / 1.2GB-HBM atomic kernel + 30.7MB f32 agg buffer); (b) CSR arrays
// overlaid with activation buffers -> bigger mchunk, fewer GEMM launches;
// (c) branch-1 GEMMs fused via stacked wt1 (N=1024) + lda support.
// ---------------------------------------------------------------------------

#define NN 60000
#define NE 960000
#define C_IN 128
#define HID 512
#define DCAT 1024
#define DFC 2048
#define DL1 4096
#define OUTC 64

typedef __bf16 bf16x8 __attribute__((ext_vector_type(8)));
typedef float floatx4 __attribute__((ext_vector_type(4)));

__device__ __forceinline__ unsigned short f2b(float f) {
  unsigned int u = __float_as_uint(f);
  unsigned int r = (u + 0x7fffu + ((u >> 16) & 1u)) >> 16;  // RNE, finite inputs
  return (unsigned short)r;
}

// async global->LDS, 16B per lane; LDS dest = wave-uniform base + lane*16
#define GLOAD_LDS16(g, l)                                                     \
  __builtin_amdgcn_global_load_lds(                                           \
      (__attribute__((address_space(1))) void*)(g),                           \
      (__attribute__((address_space(3))) void*)(l), 16, 0, 0)

// ---------------------------------------------------------------------------
// BN param fold: scale = gamma*rsqrt(var+eps); shift = (b1-mean)*scale + beta
__global__ void k_bnparams(const float* __restrict__ g,
                           const float* __restrict__ be,
                           const float* __restrict__ mn,
                           const float* __restrict__ vr,
                           const float* __restrict__ b1,
                           float* __restrict__ scale, float* __restrict__ shift) {
  int i = blockIdx.x * 256 + threadIdx.x;
  if (i < HID) {
    float s = g[i] * rsqrtf(vr[i] + 1e-5f);
    scale[i] = s;
    shift[i] = (b1[i] - mn[i]) * s + be[i];
  }
}

// fp32 [K,N] -> bf16 [N,K] transpose+downcast, 32x32 tiles
__global__ void k_transpose(const float* __restrict__ in,
                            unsigned short* __restrict__ out, int K, int N) {
  __shared__ float t[32][33];
  int n0 = blockIdx.x * 32, k0 = blockIdx.y * 32;
  int tx = threadIdx.x & 31, ty = threadIdx.x >> 5;  // 32 x 8
#pragma unroll
  for (int i = 0; i < 32; i += 8)
    t[ty + i][tx] = in[(size_t)(k0 + ty + i) * N + n0 + tx];
  __syncthreads();
#pragma unroll
  for (int i = 0; i < 32; i += 8)
    out[(size_t)(n0 + ty + i) * K + k0 + tx] = f2b(t[tx][ty + i]);
}

// ---------------------------------------------------------------------------
// CSR build: deg -> exclusive scan (3 kernels) -> bucket src ids -> gather.
__global__ void k_deg(const int* __restrict__ dst, int* __restrict__ deg) {
  int e = blockIdx.x * 256 + threadIdx.x;
  if (e < NE) atomicAdd(&deg[dst[e]], 1);
}

// per-block exclusive scan of deg; block sums to bsum
__global__ void k_scan1(const int* __restrict__ deg, int* __restrict__ offs,
                        int* __restrict__ bsum) {
  __shared__ int t[256];
  int i = blockIdx.x * 256 + threadIdx.x;
  int v = (i < NN) ? deg[i] : 0;
  t[threadIdx.x] = v;
  __syncthreads();
#pragma unroll
  for (int d = 1; d < 256; d <<= 1) {
    int add = (threadIdx.x >= d) ? t[threadIdx.x - d] : 0;
    __syncthreads();
    t[threadIdx.x] += add;
    __syncthreads();
  }
  if (i < NN) offs[i] = t[threadIdx.x] - v;  // exclusive-in-block
  if (threadIdx.x == 255) bsum[blockIdx.x] = t[255];
}

// exclusive scan of block sums (nb <= 256), single block
__global__ void k_scan2(int* __restrict__ bsum, int nb) {
  __shared__ int t[256];
  int v = (threadIdx.x < nb) ? bsum[threadIdx.x] : 0;
  t[threadIdx.x] = v;
  __syncthreads();
#pragma unroll
  for (int d = 1; d < 256; d <<= 1) {
    int add = (threadIdx.x >= d) ? t[threadIdx.x - d] : 0;
    __syncthreads();
    t[threadIdx.x] += add;
    __syncthreads();
  }
  if (threadIdx.x < nb) bsum[threadIdx.x] = t[threadIdx.x] - v;
}

__global__ void k_scan3(int* __restrict__ offs, const int* __restrict__ bsum,
                        int* __restrict__ cursor) {
  int i = blockIdx.x * 256 + threadIdx.x;
  if (i < NN) {
    int o = offs[i] + bsum[blockIdx.x];
    offs[i] = o;
    cursor[i] = o;
  }
  if (i == 0) offs[NN] = NE;
}

__global__ void k_bucket(const int* __restrict__ src, const int* __restrict__ dst,
                         int* __restrict__ cursor, int* __restrict__ esrc) {
  int e = blockIdx.x * 256 + threadIdx.x;
  if (e < NE) {
    int slot = atomicAdd(&cursor[dst[e]], 1);
    esrc[slot] = src[e];
  }
}

// one wave per node: h0[node] = bf16(x[node] + sum_j x[esrc[j]]), f32 accum
__global__ void k_agg(const float2* __restrict__ x2, const int* __restrict__ offs,
                      const int* __restrict__ esrc, unsigned int* __restrict__ h0u) {
  int node = blockIdx.x * 4 + (threadIdx.x >> 6);
  if (node >= NN) return;
  int lane = threadIdx.x & 63;
  int beg = offs[node], end = offs[node + 1];
  float2 acc = x2[(size_t)node * 64 + lane];
  for (int j = beg; j < end; j++) {
    int s = esrc[j];  // wave-uniform -> broadcast load
    float2 v = x2[(size_t)s * 64 + lane];
    acc.x += v.x;
    acc.y += v.y;
  }
  h0u[(size_t)node * 64 + lane] =
      (unsigned)f2b(acc.x) | ((unsigned)f2b(acc.y) << 16);
}

// ---------------------------------------------------------------------------
// GEMM: C[M,N] = A[M,K](row-stride lda) @ Bt[N,K]^T, bf16 in, f32 accum.
// 128x128 tile, BK=32, 4 waves (2x2), each wave 64x64 via 4x4 MFMA 16x16x32.
// LDS [oct=k/8][row][8]: global_load_lds contiguity, 2-way-aliased frag reads.
// EPI: 0=bias, 1=bias+relu, 2=bn(scale,shift)+relu, 3=bias+leaky,
//      4=bias+sigmoid -> fp32 (network output)
template <int EPI>
__global__ __launch_bounds__(256) void k_gemm(
    const unsigned short* __restrict__ A, const unsigned short* __restrict__ Bt,
    unsigned short* __restrict__ C, const float* __restrict__ bias,
    const float* __restrict__ scale, const float* __restrict__ shift,
    int M, int N, int K, int lda, int ldc) {
  __shared__ __align__(16) unsigned short lsA[4][128][8];
  __shared__ __align__(16) unsigned short lsB[4][128][8];

  const int tid = threadIdx.x;
  const int w = tid >> 6;
  const int lane = tid & 63;
  const int quad = lane >> 4;
  const int r16 = lane & 15;
  const int wm = w >> 1, wn = w & 1;
  const int m0 = blockIdx.x * 128;
  const int n0 = blockIdx.y * 128;

  const int ra0 = min(m0 + lane, M - 1);
  const int ra1 = min(m0 + 64 + lane, M - 1);
  const int rb0 = min(n0 + lane, N - 1);
  const int rb1 = min(n0 + 64 + lane, N - 1);
  const unsigned short* pA0 = A + (size_t)ra0 * lda + w * 8;
  const unsigned short* pA1 = A + (size_t)ra1 * lda + w * 8;
  const unsigned short* pB0 = Bt + (size_t)rb0 * K + w * 8;
  const unsigned short* pB1 = Bt + (size_t)rb1 * K + w * 8;

  floatx4 acc[4][4];
#pragma unroll
  for (int i = 0; i < 4; i++)
#pragma unroll
    for (int j = 0; j < 4; j++) acc[i][j] = (floatx4){0.f, 0.f, 0.f, 0.f};

  for (int k0 = 0; k0 < K; k0 += 32) {
    GLOAD_LDS16(pA0, &lsA[w][0][0]);
    GLOAD_LDS16(pA1, &lsA[w][64][0]);
    GLOAD_LDS16(pB0, &lsB[w][0][0]);
    GLOAD_LDS16(pB1, &lsB[w][64][0]);
    pA0 += 32; pA1 += 32; pB0 += 32; pB1 += 32;
    __syncthreads();

    bf16x8 af[4], bfr[4];
#pragma unroll
    for (int i = 0; i < 4; i++)
      af[i] = *(const bf16x8*)&lsA[quad][wm * 64 + i * 16 + r16][0];
#pragma unroll
    for (int j = 0; j < 4; j++)
      bfr[j] = *(const bf16x8*)&lsB[quad][wn * 64 + j * 16 + r16][0];
#pragma unroll
    for (int i = 0; i < 4; i++)
#pragma unroll
      for (int j = 0; j < 4; j++)
        acc[i][j] = __builtin_amdgcn_mfma_f32_16x16x32_bf16(af[i], bfr[j],
                                                            acc[i][j], 0, 0, 0);
    __syncthreads();
  }

  // epilogue: C/D layout col=lane&15, row=quad*4+reg  [m89-verified]
#pragma unroll
  for (int j = 0; j < 4; j++) {
    int gn = n0 + wn * 64 + j * 16 + r16;
    int cn = gn < N ? gn : 0;
    float p0, p1 = 0.f;
    if constexpr (EPI == 2) {
      p0 = scale[cn];
      p1 = shift[cn];
    } else {
      p0 = bias[cn];
    }
#pragma unroll
    for (int i = 0; i < 4; i++) {
#pragma unroll
      for (int t = 0; t < 4; t++) {
        int gm = m0 + wm * 64 + i * 16 + quad * 4 + t;
        if (gm < M && gn < N) {
          float v = acc[i][j][t];
          if constexpr (EPI == 0) {
            v += p0;
            C[(size_t)gm * ldc + gn] = f2b(v);
          } else if constexpr (EPI == 1) {
            v += p0; v = v > 0.f ? v : 0.f;
            C[(size_t)gm * ldc + gn] = f2b(v);
          } else if constexpr (EPI == 2) {
            v = v * p0 + p1; v = v > 0.f ? v : 0.f;
            C[(size_t)gm * ldc + gn] = f2b(v);
          } else if constexpr (EPI == 3) {
            v += p0; v = v > 0.f ? v : 0.01f * v;
            C[(size_t)gm * ldc + gn] = f2b(v);
          } else {  // sigmoid -> fp32 network output
            v += p0;
            v = 1.f / (1.f + __expf(-v));
            ((float*)C)[(size_t)gm * ldc + gn] = v;
          }
        }
      }
    }
  }
}

// ---------------------------------------------------------------------------
extern "C" void kernel_launch(void* const* d_in, const int* in_sizes, int n_in,
                              void* d_out, int out_size, void* d_ws,
                              size_t ws_size, hipStream_t stream) {
  typedef const float* cf;
  cf x = (cf)d_in[0];
  const int* ei = (const int*)d_in[1];
  const int* srcI = ei;
  const int* dstI = ei + NE;
  cf w1a = (cf)d_in[2],  b1a = (cf)d_in[3];
  cf ga = (cf)d_in[4],   bea = (cf)d_in[5];
  cf mna = (cf)d_in[6],  vra = (cf)d_in[7];
  cf w2a = (cf)d_in[8],  b2a = (cf)d_in[9];
  cf w1b = (cf)d_in[10], b1b = (cf)d_in[11];
  cf gb = (cf)d_in[12],  beb = (cf)d_in[13];
  cf mnb = (cf)d_in[14], vrb = (cf)d_in[15];
  cf w2b = (cf)d_in[16], b2b = (cf)d_in[17];
  cf fc_w = (cf)d_in[18], fc_b = (cf)d_in[19];
  cf l1_w = (cf)d_in[20], l1_b = (cf)d_in[21];
  cf l2_w = (cf)d_in[22], l2_b = (cf)d_in[23];
  cf ow = (cf)d_in[24],   ob = (cf)d_in[25];
  float* outf = (float*)d_out;

  // ---- workspace carve-up ----------------------------------------------------
  char* ws = (char*)d_ws;
  size_t off = 0;
  auto carve = [&](size_t bytes) {
    void* p = ws + off;
    off += (bytes + 255) & ~(size_t)255;
    return p;
  };
  // persistent (~53 MB): transposed weights + h0 + folded BN params
  unsigned short* wt1ab = (unsigned short*)carve((size_t)DCAT * C_IN * 2);  // [1024][128]
  unsigned short* wt2a = (unsigned short*)carve((size_t)HID * HID * 2);
  unsigned short* wt2b = (unsigned short*)carve((size_t)HID * HID * 2);
  unsigned short* wtfc = (unsigned short*)carve((size_t)DFC * DCAT * 2);
  unsigned short* wtl1 = (unsigned short*)carve((size_t)DL1 * DFC * 2);
  unsigned short* wtl2 = (unsigned short*)carve((size_t)DFC * DL1 * 2);
  unsigned short* wtout = (unsigned short*)carve((size_t)OUTC * DFC * 2);
  float* scale_ab = (float*)carve(DCAT * 4);
  float* shift_ab = (float*)carve(DCAT * 4);
  unsigned short* h0 = (unsigned short*)carve((size_t)NN * C_IN * 2);

  // phase-1-only CSR arrays, OVERLAID with phase-2 activation buffers
  size_t off_overlay = off;
  int* deg = (int*)carve((size_t)NN * 4);
  int* offs = (int*)carve((size_t)(NN + 1) * 4);
  int* cursor = (int*)carve((size_t)NN * 4);
  int* bsum = (int*)carve(256 * 4);
  int* esrc = (int*)carve((size_t)NE * 4);
  size_t off_csr_end = off;

  // phase-2 activations from the overlay region start
  off = off_overlay;
  size_t rem = (ws_size > off + 4096) ? (ws_size - off - 4096) : 0;
  int mchunk = (int)(rem / ((DFC + DL1) * 2));
  if (mchunk > 15104) mchunk = 15104;
  mchunk &= ~127;
  if (mchunk < 128) mchunk = 128;
  unsigned short* bufA = (unsigned short*)carve((size_t)mchunk * DFC * 2);
  unsigned short* bufB = (unsigned short*)carve((size_t)mchunk * DL1 * 2);
  (void)in_sizes; (void)n_in; (void)out_size; (void)off_csr_end;

  // ---- phase 0: params + weight transposes ----------------------------------
  k_bnparams<<<2, 256, 0, stream>>>(ga, bea, mna, vra, b1a, scale_ab, shift_ab);
  k_bnparams<<<2, 256, 0, stream>>>(gb, beb, mnb, vrb, b1b, scale_ab + HID,
                                    shift_ab + HID);
  k_transpose<<<dim3(HID / 32, C_IN / 32), 256, 0, stream>>>(w1a, wt1ab, C_IN, HID);
  k_transpose<<<dim3(HID / 32, C_IN / 32), 256, 0, stream>>>(
      w1b, wt1ab + (size_t)HID * C_IN, C_IN, HID);
  k_transpose<<<dim3(HID / 32, HID / 32), 256, 0, stream>>>(w2a, wt2a, HID, HID);
  k_transpose<<<dim3(HID / 32, HID / 32), 256, 0, stream>>>(w2b, wt2b, HID, HID);
  k_transpose<<<dim3(DFC / 32, DCAT / 32), 256, 0, stream>>>(fc_w, wtfc, DCAT, DFC);
  k_transpose<<<dim3(DL1 / 32, DFC / 32), 256, 0, stream>>>(l1_w, wtl1, DFC, DL1);
  k_transpose<<<dim3(DFC / 32, DL1 / 32), 256, 0, stream>>>(l2_w, wtl2, DL1, DFC);
  k_transpose<<<dim3(OUTC / 32, DFC / 32), 256, 0, stream>>>(ow, wtout, DFC, OUTC);

  // ---- phase 1: CSR build + gather aggregation -------------------------------
  const int NB_NODE = (NN + 255) / 256;  // 235 blocks
  hipMemsetAsync(deg, 0, (size_t)NN * 4, stream);
  k_deg<<<(NE + 255) / 256, 256, 0, stream>>>(dstI, deg);
  k_scan1<<<NB_NODE, 256, 0, stream>>>(deg, offs, bsum);
  k_scan2<<<1, 256, 0, stream>>>(bsum, NB_NODE);
  k_scan3<<<NB_NODE, 256, 0, stream>>>(offs, bsum, cursor);
  k_bucket<<<(NE + 255) / 256, 256, 0, stream>>>(srcI, dstI, cursor, esrc);
  k_agg<<<(NN + 3) / 4, 256, 0, stream>>>((const float2*)x, offs, esrc,
                                          (unsigned int*)h0);

  // ---- phase 2: GEMM chain, M in adaptive chunks -----------------------------
  auto gemm = [&](int epi, const unsigned short* A, const unsigned short* Bt,
                  unsigned short* Cp, cf bias, const float* sc, const float* sh,
                  int M, int N, int K, int lda, int ldc) {
    dim3 g((M + 127) / 128, (N + 127) / 128);
    switch (epi) {
      case 0: k_gemm<0><<<g, 256, 0, stream>>>(A, Bt, Cp, bias, sc, sh, M, N, K, lda, ldc); break;
      case 1: k_gemm<1><<<g, 256, 0, stream>>>(A, Bt, Cp, bias, sc, sh, M, N, K, lda, ldc); break;
      case 2: k_gemm<2><<<g, 256, 0, stream>>>(A, Bt, Cp, bias, sc, sh, M, N, K, lda, ldc); break;
      case 3: k_gemm<3><<<g, 256, 0, stream>>>(A, Bt, Cp, bias, sc, sh, M, N, K, lda, ldc); break;
      default: k_gemm<4><<<g, 256, 0, stream>>>(A, Bt, Cp, bias, sc, sh, M, N, K, lda, ldc); break;
    }
  };

  for (int m0 = 0; m0 < NN; m0 += mchunk) {
    const int M = (NN - m0 < mchunk) ? (NN - m0) : mchunk;
    const unsigned short* h0c = h0 + (size_t)m0 * C_IN;
    unsigned short* outc = (unsigned short*)(outf + (size_t)m0 * OUTC);
    // fused branch-1: t1 = BN+ReLU(h0 @ [w1a|w1b])  (M x 1024), in bufA ld=1024
    gemm(2, h0c, wt1ab, bufA, nullptr, scale_ab, shift_ab, M, DCAT, C_IN, C_IN, DCAT);
    // branch-2a/b: xcat halves (bufB, ld=1024)
    gemm(1, bufA, wt2a, bufB, b2a, nullptr, nullptr, M, HID, HID, DCAT, DCAT);
    gemm(1, bufA + HID, wt2b, bufB + HID, b2b, nullptr, nullptr, M, HID, HID, DCAT, DCAT);
    // head: xcat(bufB,1024) -> hfc(bufA,2048) -> hl1(bufB,4096) -> hl2(bufA,2048) -> out(fp32)
    gemm(3, bufB, wtfc, bufA, fc_b, nullptr, nullptr, M, DFC, DCAT, DCAT, DFC);
    gemm(0, bufA, wtl1, bufB, l1_b, nullptr, nullptr, M, DL1, DFC, DFC, DL1);
    gemm(0, bufB, wtl2, bufA, l2_b, nullptr, nullptr, M, DFC, DL1, DL1, DFC);
    gemm(4, bufA, wtout, outc, ob, nullptr, nullptr, M, OUTC, DFC, DFC, OUTC);
  }
}

// Round 5
// 5536.366 us; speedup vs baseline: 1.2330x; 1.0740x over previous
//
#include <hip/hip_runtime.h>

// ---------------------------------------------------------------------------
// GCNConvNet: 2x GIN conv (shared aggregation) + dense head. fp32 I/O,
// bf16 MFMA internally (harness grants bf16 tolerance).
// Round 5: GEMM latency fixes (r4: MfmaUtil 17%, FETCH 6x compulsory):
//   (a) single-barrier double-buffered K-loop: prefetch tile k+1 via
//       global_load_lds AFTER the barrier, compute tile k from other stage;
//       the vmcnt drain then waits on loads issued a full compute-phase ago.
//   (b) supertile swizzle (GM=8) for L2/L3 locality of A/B tiles.
// CSR-gather aggregation unchanged (r4 win).
// ---------------------------------------------------------------------------

#define NN 60000
#define NE 960000
#define C_IN 128
#define HID 512
#define DCAT 1024
#define DFC 2048
#define DL1 4096
#define OUTC 64

typedef __bf16 bf16x8 __attribute__((ext_vector_type(8)));
typedef float floatx4 __attribute__((ext_vector_type(4)));

__device__ __forceinline__ unsigned short f2b(float f) {
  unsigned int u = __float_as_uint(f);
  unsigned int r = (u + 0x7fffu + ((u >> 16) & 1u)) >> 16;  // RNE, finite inputs
  return (unsigned short)r;
}

// async global->LDS, 16B per lane; LDS dest = wave-uniform base + lane*16
#define GLOAD_LDS16(g, l)                                                     \
  __builtin_amdgcn_global_load_lds(                                           \
      (__attribute__((address_space(1))) void*)(g),                           \
      (__attribute__((address_space(3))) void*)(l), 16, 0, 0)

// ---------------------------------------------------------------------------
__global__ void k_bnparams(const float* __restrict__ g,
                           const float* __restrict__ be,
                           const float* __restrict__ mn,
                           const float* __restrict__ vr,
                           const float* __restrict__ b1,
                           float* __restrict__ scale, float* __restrict__ shift) {
  int i = blockIdx.x * 256 + threadIdx.x;
  if (i < HID) {
    float s = g[i] * rsqrtf(vr[i] + 1e-5f);
    scale[i] = s;
    shift[i] = (b1[i] - mn[i]) * s + be[i];
  }
}

// fp32 [K,N] -> bf16 [N,K] transpose+downcast, 32x32 tiles
__global__ void k_transpose(const float* __restrict__ in,
                            unsigned short* __restrict__ out, int K, int N) {
  __shared__ float t[32][33];
  int n0 = blockIdx.x * 32, k0 = blockIdx.y * 32;
  int tx = threadIdx.x & 31, ty = threadIdx.x >> 5;  // 32 x 8
#pragma unroll
  for (int i = 0; i < 32; i += 8)
    t[ty + i][tx] = in[(size_t)(k0 + ty + i) * N + n0 + tx];
  __syncthreads();
#pragma unroll
  for (int i = 0; i < 32; i += 8)
    out[(size_t)(n0 + ty + i) * K + k0 + tx] = f2b(t[tx][ty + i]);
}

// ---------------------------------------------------------------------------
// CSR build: deg -> exclusive scan (3 kernels) -> bucket src ids -> gather.
__global__ void k_deg(const int* __restrict__ dst, int* __restrict__ deg) {
  int e = blockIdx.x * 256 + threadIdx.x;
  if (e < NE) atomicAdd(&deg[dst[e]], 1);
}

__global__ void k_scan1(const int* __restrict__ deg, int* __restrict__ offs,
                        int* __restrict__ bsum) {
  __shared__ int t[256];
  int i = blockIdx.x * 256 + threadIdx.x;
  int v = (i < NN) ? deg[i] : 0;
  t[threadIdx.x] = v;
  __syncthreads();
#pragma unroll
  for (int d = 1; d < 256; d <<= 1) {
    int add = (threadIdx.x >= d) ? t[threadIdx.x - d] : 0;
    __syncthreads();
    t[threadIdx.x] += add;
    __syncthreads();
  }
  if (i < NN) offs[i] = t[threadIdx.x] - v;
  if (threadIdx.x == 255) bsum[blockIdx.x] = t[255];
}

__global__ void k_scan2(int* __restrict__ bsum, int nb) {
  __shared__ int t[256];
  int v = (threadIdx.x < nb) ? bsum[threadIdx.x] : 0;
  t[threadIdx.x] = v;
  __syncthreads();
#pragma unroll
  for (int d = 1; d < 256; d <<= 1) {
    int add = (threadIdx.x >= d) ? t[threadIdx.x - d] : 0;
    __syncthreads();
    t[threadIdx.x] += add;
    __syncthreads();
  }
  if (threadIdx.x < nb) bsum[threadIdx.x] = t[threadIdx.x] - v;
}

__global__ void k_scan3(int* __restrict__ offs, const int* __restrict__ bsum,
                        int* __restrict__ cursor) {
  int i = blockIdx.x * 256 + threadIdx.x;
  if (i < NN) {
    int o = offs[i] + bsum[blockIdx.x];
    offs[i] = o;
    cursor[i] = o;
  }
  if (i == 0) offs[NN] = NE;
}

__global__ void k_bucket(const int* __restrict__ src, const int* __restrict__ dst,
                         int* __restrict__ cursor, int* __restrict__ esrc) {
  int e = blockIdx.x * 256 + threadIdx.x;
  if (e < NE) {
    int slot = atomicAdd(&cursor[dst[e]], 1);
    esrc[slot] = src[e];
  }
}

// one wave per node: h0[node] = bf16(x[node] + sum_j x[esrc[j]]), f32 accum
__global__ void k_agg(const float2* __restrict__ x2, const int* __restrict__ offs,
                      const int* __restrict__ esrc, unsigned int* __restrict__ h0u) {
  int node = blockIdx.x * 4 + (threadIdx.x >> 6);
  if (node >= NN) return;
  int lane = threadIdx.x & 63;
  int beg = offs[node], end = offs[node + 1];
  float2 acc = x2[(size_t)node * 64 + lane];
  for (int j = beg; j < end; j++) {
    int s = esrc[j];  // wave-uniform -> broadcast load
    float2 v = x2[(size_t)s * 64 + lane];
    acc.x += v.x;
    acc.y += v.y;
  }
  h0u[(size_t)node * 64 + lane] =
      (unsigned)f2b(acc.x) | ((unsigned)f2b(acc.y) << 16);
}

// ---------------------------------------------------------------------------
// GEMM: C[M,N] = A[M,K](row-stride lda) @ Bt[N,K]^T, bf16 in, f32 accum.
// 128x128 tile, BK=32, 4 waves (2x2), each wave 64x64 via 4x4 MFMA 16x16x32.
// Double-buffered LDS, ONE barrier per K-iter: prefetch stage s^1 issued
// after the barrier, compute from stage s; the per-wave vmcnt drain at the
// NEXT barrier waits on loads issued a full compute phase earlier.
// Supertile swizzle: 1D grid, groups of GM=8 M-tiles sweep all N-tiles.
// EPI: 0=bias, 1=bias+relu, 2=bn+relu, 3=bias+leaky, 4=bias+sigmoid->fp32
template <int EPI>
__global__ __launch_bounds__(256) void k_gemm(
    const unsigned short* __restrict__ A, const unsigned short* __restrict__ Bt,
    unsigned short* __restrict__ C, const float* __restrict__ bias,
    const float* __restrict__ scale, const float* __restrict__ shift,
    int M, int N, int K, int lda, int ldc) {
  __shared__ __align__(16) unsigned short lsA[2][4][128][8];
  __shared__ __align__(16) unsigned short lsB[2][4][128][8];

  const int tid = threadIdx.x;
  const int w = tid >> 6;
  const int lane = tid & 63;
  const int quad = lane >> 4;
  const int r16 = lane & 15;
  const int wm = w >> 1, wn = w & 1;

  // ---- supertile swizzle (GM M-tiles per group, sweep all N-tiles) ----
  const int GM = 8;
  const int mt_total = (M + 127) >> 7, nt_total = (N + 127) >> 7;
  const int full = (mt_total / GM) * GM;
  const int boundary = full * nt_total;
  int mt, nt;
  {
    int id = blockIdx.x;
    if (id < boundary) {
      int per_group = GM * nt_total;
      int g = id / per_group, r = id % per_group;
      mt = g * GM + r % GM;
      nt = r / GM;
    } else {
      int r = id - boundary, gm = mt_total - full;
      mt = full + r % gm;
      nt = r / gm;
    }
  }
  const int m0 = mt << 7;
  const int n0 = nt << 7;

  const int ra0 = min(m0 + lane, M - 1);
  const int ra1 = min(m0 + 64 + lane, M - 1);
  const int rb0 = min(n0 + lane, N - 1);
  const int rb1 = min(n0 + 64 + lane, N - 1);
  const unsigned short* pA0 = A + (size_t)ra0 * lda + w * 8;
  const unsigned short* pA1 = A + (size_t)ra1 * lda + w * 8;
  const unsigned short* pB0 = Bt + (size_t)rb0 * K + w * 8;
  const unsigned short* pB1 = Bt + (size_t)rb1 * K + w * 8;

  floatx4 acc[4][4];
#pragma unroll
  for (int i = 0; i < 4; i++)
#pragma unroll
    for (int j = 0; j < 4; j++) acc[i][j] = (floatx4){0.f, 0.f, 0.f, 0.f};

  // prologue: stage 0 loads
  GLOAD_LDS16(pA0, &lsA[0][w][0][0]);
  GLOAD_LDS16(pA1, &lsA[0][w][64][0]);
  GLOAD_LDS16(pB0, &lsB[0][w][0][0]);
  GLOAD_LDS16(pB1, &lsB[0][w][64][0]);

  int s = 0;
  for (int k0 = 0; k0 < K; k0 += 32, s ^= 1) {
    __syncthreads();  // drains THIS wave's stage-s loads (issued 1 iter ago)
    if (k0 + 32 < K) {
      pA0 += 32; pA1 += 32; pB0 += 32; pB1 += 32;
      GLOAD_LDS16(pA0, &lsA[s ^ 1][w][0][0]);
      GLOAD_LDS16(pA1, &lsA[s ^ 1][w][64][0]);
      GLOAD_LDS16(pB0, &lsB[s ^ 1][w][0][0]);
      GLOAD_LDS16(pB1, &lsB[s ^ 1][w][64][0]);
    }
    bf16x8 af[4], bfr[4];
#pragma unroll
    for (int i = 0; i < 4; i++)
      af[i] = *(const bf16x8*)&lsA[s][quad][wm * 64 + i * 16 + r16][0];
#pragma unroll
    for (int j = 0; j < 4; j++)
      bfr[j] = *(const bf16x8*)&lsB[s][quad][wn * 64 + j * 16 + r16][0];
#pragma unroll
    for (int i = 0; i < 4; i++)
#pragma unroll
      for (int j = 0; j < 4; j++)
        acc[i][j] = __builtin_amdgcn_mfma_f32_16x16x32_bf16(af[i], bfr[j],
                                                            acc[i][j], 0, 0, 0);
  }

  // epilogue: C/D layout col=lane&15, row=quad*4+reg  [m89-verified]
#pragma unroll
  for (int j = 0; j < 4; j++) {
    int gn = n0 + wn * 64 + j * 16 + r16;
    int cn = gn < N ? gn : 0;
    float p0, p1 = 0.f;
    if constexpr (EPI == 2) {
      p0 = scale[cn];
      p1 = shift[cn];
    } else {
      p0 = bias[cn];
    }
#pragma unroll
    for (int i = 0; i < 4; i++) {
#pragma unroll
      for (int t = 0; t < 4; t++) {
        int gm = m0 + wm * 64 + i * 16 + quad * 4 + t;
        if (gm < M && gn < N) {
          float v = acc[i][j][t];
          if constexpr (EPI == 0) {
            v += p0;
            C[(size_t)gm * ldc + gn] = f2b(v);
          } else if constexpr (EPI == 1) {
            v += p0; v = v > 0.f ? v : 0.f;
            C[(size_t)gm * ldc + gn] = f2b(v);
          } else if constexpr (EPI == 2) {
            v = v * p0 + p1; v = v > 0.f ? v : 0.f;
            C[(size_t)gm * ldc + gn] = f2b(v);
          } else if constexpr (EPI == 3) {
            v += p0; v = v > 0.f ? v : 0.01f * v;
            C[(size_t)gm * ldc + gn] = f2b(v);
          } else {  // sigmoid -> fp32 network output
            v += p0;
            v = 1.f / (1.f + __expf(-v));
            ((float*)C)[(size_t)gm * ldc + gn] = v;
          }
        }
      }
    }
  }
}

// ---------------------------------------------------------------------------
extern "C" void kernel_launch(void* const* d_in, const int* in_sizes, int n_in,
                              void* d_out, int out_size, void* d_ws,
                              size_t ws_size, hipStream_t stream) {
  typedef const float* cf;
  cf x = (cf)d_in[0];
  const int* ei = (const int*)d_in[1];
  const int* srcI = ei;
  const int* dstI = ei + NE;
  cf w1a = (cf)d_in[2],  b1a = (cf)d_in[3];
  cf ga = (cf)d_in[4],   bea = (cf)d_in[5];
  cf mna = (cf)d_in[6],  vra = (cf)d_in[7];
  cf w2a = (cf)d_in[8],  b2a = (cf)d_in[9];
  cf w1b = (cf)d_in[10], b1b = (cf)d_in[11];
  cf gb = (cf)d_in[12],  beb = (cf)d_in[13];
  cf mnb = (cf)d_in[14], vrb = (cf)d_in[15];
  cf w2b = (cf)d_in[16], b2b = (cf)d_in[17];
  cf fc_w = (cf)d_in[18], fc_b = (cf)d_in[19];
  cf l1_w = (cf)d_in[20], l1_b = (cf)d_in[21];
  cf l2_w = (cf)d_in[22], l2_b = (cf)d_in[23];
  cf ow = (cf)d_in[24],   ob = (cf)d_in[25];
  float* outf = (float*)d_out;

  // ---- workspace carve-up ----------------------------------------------------
  char* ws = (char*)d_ws;
  size_t off = 0;
  auto carve = [&](size_t bytes) {
    void* p = ws + off;
    off += (bytes + 255) & ~(size_t)255;
    return p;
  };
  // persistent (~53 MB): transposed weights + h0 + folded BN params
  unsigned short* wt1ab = (unsigned short*)carve((size_t)DCAT * C_IN * 2);
  unsigned short* wt2a = (unsigned short*)carve((size_t)HID * HID * 2);
  unsigned short* wt2b = (unsigned short*)carve((size_t)HID * HID * 2);
  unsigned short* wtfc = (unsigned short*)carve((size_t)DFC * DCAT * 2);
  unsigned short* wtl1 = (unsigned short*)carve((size_t)DL1 * DFC * 2);
  unsigned short* wtl2 = (unsigned short*)carve((size_t)DFC * DL1 * 2);
  unsigned short* wtout = (unsigned short*)carve((size_t)OUTC * DFC * 2);
  float* scale_ab = (float*)carve(DCAT * 4);
  float* shift_ab = (float*)carve(DCAT * 4);
  unsigned short* h0 = (unsigned short*)carve((size_t)NN * C_IN * 2);

  // phase-1-only CSR arrays, OVERLAID with phase-2 activation buffers
  size_t off_overlay = off;
  int* deg = (int*)carve((size_t)NN * 4);
  int* offs = (int*)carve((size_t)(NN + 1) * 4);
  int* cursor = (int*)carve((size_t)NN * 4);
  int* bsum = (int*)carve(256 * 4);
  int* esrc = (int*)carve((size_t)NE * 4);

  // phase-2 activations from the overlay region start
  off = off_overlay;
  size_t rem = (ws_size > off + 4096) ? (ws_size - off - 4096) : 0;
  int mchunk = (int)(rem / ((DFC + DL1) * 2));
  if (mchunk > 15104) mchunk = 15104;
  mchunk &= ~127;
  if (mchunk < 128) mchunk = 128;
  unsigned short* bufA = (unsigned short*)carve((size_t)mchunk * DFC * 2);
  unsigned short* bufB = (unsigned short*)carve((size_t)mchunk * DL1 * 2);
  (void)in_sizes; (void)n_in; (void)out_size;

  // ---- phase 0: params + weight transposes ----------------------------------
  k_bnparams<<<2, 256, 0, stream>>>(ga, bea, mna, vra, b1a, scale_ab, shift_ab);
  k_bnparams<<<2, 256, 0, stream>>>(gb, beb, mnb, vrb, b1b, scale_ab + HID,
                                    shift_ab + HID);
  k_transpose<<<dim3(HID / 32, C_IN / 32), 256, 0, stream>>>(w1a, wt1ab, C_IN, HID);
  k_transpose<<<dim3(HID / 32, C_IN / 32), 256, 0, stream>>>(
      w1b, wt1ab + (size_t)HID * C_IN, C_IN, HID);
  k_transpose<<<dim3(HID / 32, HID / 32), 256, 0, stream>>>(w2a, wt2a, HID, HID);
  k_transpose<<<dim3(HID / 32, HID / 32), 256, 0, stream>>>(w2b, wt2b, HID, HID);
  k_transpose<<<dim3(DFC / 32, DCAT / 32), 256, 0, stream>>>(fc_w, wtfc, DCAT, DFC);
  k_transpose<<<dim3(DL1 / 32, DFC / 32), 256, 0, stream>>>(l1_w, wtl1, DFC, DL1);
  k_transpose<<<dim3(DFC / 32, DL1 / 32), 256, 0, stream>>>(l2_w, wtl2, DL1, DFC);
  k_transpose<<<dim3(OUTC / 32, DFC / 32), 256, 0, stream>>>(ow, wtout, DFC, OUTC);

  // ---- phase 1: CSR build + gather aggregation -------------------------------
  const int NB_NODE = (NN + 255) / 256;
  hipMemsetAsync(deg, 0, (size_t)NN * 4, stream);
  k_deg<<<(NE + 255) / 256, 256, 0, stream>>>(dstI, deg);
  k_scan1<<<NB_NODE, 256, 0, stream>>>(deg, offs, bsum);
  k_scan2<<<1, 256, 0, stream>>>(bsum, NB_NODE);
  k_scan3<<<NB_NODE, 256, 0, stream>>>(offs, bsum, cursor);
  k_bucket<<<(NE + 255) / 256, 256, 0, stream>>>(srcI, dstI, cursor, esrc);
  k_agg<<<(NN + 3) / 4, 256, 0, stream>>>((const float2*)x, offs, esrc,
                                          (unsigned int*)h0);

  // ---- phase 2: GEMM chain, M in adaptive chunks -----------------------------
  auto gemm = [&](int epi, const unsigned short* A, const unsigned short* Bt,
                  unsigned short* Cp, cf bias, const float* sc, const float* sh,
                  int M, int N, int K, int lda, int ldc) {
    dim3 g(((M + 127) / 128) * ((N + 127) / 128));
    switch (epi) {
      case 0: k_gemm<0><<<g, 256, 0, stream>>>(A, Bt, Cp, bias, sc, sh, M, N, K, lda, ldc); break;
      case 1: k_gemm<1><<<g, 256, 0, stream>>>(A, Bt, Cp, bias, sc, sh, M, N, K, lda, ldc); break;
      case 2: k_gemm<2><<<g, 256, 0, stream>>>(A, Bt, Cp, bias, sc, sh, M, N, K, lda, ldc); break;
      case 3: k_gemm<3><<<g, 256, 0, stream>>>(A, Bt, Cp, bias, sc, sh, M, N, K, lda, ldc); break;
      default: k_gemm<4><<<g, 256, 0, stream>>>(A, Bt, Cp, bias, sc, sh, M, N, K, lda, ldc); break;
    }
  };

  for (int m0 = 0; m0 < NN; m0 += mchunk) {
    const int M = (NN - m0 < mchunk) ? (NN - m0) : mchunk;
    const unsigned short* h0c = h0 + (size_t)m0 * C_IN;
    unsigned short* outc = (unsigned short*)(outf + (size_t)m0 * OUTC);
    // fused branch-1: t1 = BN+ReLU(h0 @ [w1a|w1b])  (M x 1024), bufA ld=1024
    gemm(2, h0c, wt1ab, bufA, nullptr, scale_ab, shift_ab, M, DCAT, C_IN, C_IN, DCAT);
    // branch-2a/b: xcat halves (bufB, ld=1024)
    gemm(1, bufA, wt2a, bufB, b2a, nullptr, nullptr, M, HID, HID, DCAT, DCAT);
    gemm(1, bufA + HID, wt2b, bufB + HID, b2b, nullptr, nullptr, M, HID, HID, DCAT, DCAT);
    // head: xcat(bufB,1024) -> hfc(bufA,2048) -> hl1(bufB,4096) -> hl2(bufA,2048) -> out(fp32)
    gemm(3, bufB, wtfc, bufA, fc_b, nullptr, nullptr, M, DFC, DCAT, DCAT, DFC);
    gemm(0, bufA, wtl1, bufB, l1_b, nullptr, nullptr, M, DL1, DFC, DFC, DL1);
    gemm(0, bufB, wtl2, bufA, l2_b, nullptr, nullptr, M, DFC, DL1, DL1, DFC);
    gemm(4, bufA, wtout, outc, ob, nullptr, nullptr, M, OUTC, DFC, DFC, OUTC);
  }
}